// Round 1
// baseline (1608.689 us; speedup 1.0000x reference)
//
#include <hip/hip_runtime.h>
#include <math.h>

#define N_NODES 10000
#define N_EDGES 160000
#define BATCH 32
#define HLEN 12
#define KORD 25
#define G1 32
#define NCLS 10
#define BH 384   /* BATCH*HLEN */
#define BG 1024  /* BATCH*G1  */

// ---------------- CSR build ----------------
__global__ void deg_kernel(const int* __restrict__ row, int* __restrict__ cnt) {
    int e = blockIdx.x * 256 + threadIdx.x;
    if (e < N_EDGES) atomicAdd(&cnt[row[e]], 1);
}

__global__ void dinv_kernel(const int* __restrict__ cnt, float* __restrict__ dinv) {
    int n = blockIdx.x * 256 + threadIdx.x;
    if (n < N_NODES) {
        int d = cnt[n];
        dinv[n] = (d > 0) ? 1.0f / sqrtf((float)d) : 0.0f;
    }
}

__global__ __launch_bounds__(1024) void scan_kernel(const int* __restrict__ cnt,
                                                    int* __restrict__ rowstart) {
    __shared__ int sums[1024];
    int t = threadIdx.x;
    const int per = 10; // 1024*10 >= 10000
    int base = t * per;
    int s = 0;
    for (int i = 0; i < per; i++) { int idx = base + i; if (idx < N_NODES) s += cnt[idx]; }
    sums[t] = s;
    __syncthreads();
    for (int off = 1; off < 1024; off <<= 1) {
        int v = 0;
        if (t >= off) v = sums[t - off];
        __syncthreads();
        sums[t] += v;
        __syncthreads();
    }
    int run = sums[t] - s; // exclusive prefix for this chunk
    for (int i = 0; i < per; i++) {
        int idx = base + i;
        if (idx < N_NODES) { rowstart[idx] = run; run += cnt[idx]; }
    }
    if (t == 1023) rowstart[N_NODES] = run;
}

__global__ void scatter_kernel(const int* __restrict__ row, const int* __restrict__ col,
                               const float* __restrict__ dinv,
                               const int* __restrict__ rowstart, int* __restrict__ cursor,
                               int* __restrict__ csr_col, float* __restrict__ csr_norm) {
    int e = blockIdx.x * 256 + threadIdx.x;
    if (e < N_EDGES) {
        int r = row[e], c = col[e];
        int p = rowstart[r] + atomicAdd(&cursor[r], 1);
        csr_col[p] = c;
        csr_norm[p] = -dinv[r] * dinv[c];
    }
}

// ---------------- FFT (real part, H=12 cosine transform) ----------------
// x: [B, N, H] b-major.  xf: [N, B*H] node-major.
__global__ __launch_bounds__(256) void fft_kernel(const float* __restrict__ x,
                                                  float* __restrict__ xf) {
    __shared__ float C[HLEN][HLEN];
    int t = threadIdx.x;
    if (t < HLEN * HLEN) {
        int k = t / HLEN, tt = t % HLEN;
        C[k][tt] = cosf(0.52359877559829887308f * (float)(k * tt)); // pi/6 * k*t
    }
    __syncthreads();
    int tid = blockIdx.x * 256 + t; // tid = n*32 + b
    if (tid >= N_NODES * BATCH) return;
    int n = tid >> 5, b = tid & 31;
    const float* xp = x + (size_t)b * (N_NODES * HLEN) + (size_t)n * HLEN;
    float xr[HLEN];
#pragma unroll
    for (int i = 0; i < HLEN; i++) xr[i] = xp[i];
    float* o = xf + (size_t)n * BH + b * HLEN;
#pragma unroll
    for (int k = 0; k < HLEN; k++) {
        float s = 0.f;
#pragma unroll
        for (int i = 0; i < HLEN; i++) s += xr[i] * C[k][i];
        o[k] = s;
    }
}

// ---------------- k=0 einsum (initializes out) ----------------
__global__ __launch_bounds__(256) void k0_kernel(const float* __restrict__ z,
                                                 float* __restrict__ out,
                                                 const float* __restrict__ w0) {
    __shared__ float lds[4][BH];
    __shared__ float wk[BH];
    int t = threadIdx.x;
    for (int i = t; i < BH; i += 256) wk[i] = w0[i];
    int wv = t >> 6, lane = t & 63;
    int node = blockIdx.x * 4 + wv;
    const float* zp = z + (size_t)node * BH + lane;
#pragma unroll
    for (int j = 0; j < 6; j++) lds[wv][lane + 64 * j] = zp[64 * j];
    __syncthreads();
    float* op = out + (size_t)node * BG;
#pragma unroll
    for (int j2 = 0; j2 < 16; j2++) {
        int idx = lane + 64 * j2;
        int b = idx >> 5, f = idx & 31;
        float s = 0.f;
#pragma unroll
        for (int h = 0; h < HLEN; h++) s += lds[wv][b * HLEN + h] * wk[h * G1 + f];
        op[idx] = s;
    }
}

// ---------------- fused prop + einsum accumulate ----------------
// tx_next = alpha * (Lt @ z_cur) - beta * z_prev ; out += tx_next @ Wk
// znext may alias zprev (each element read before written, by its own thread).
__global__ __launch_bounds__(256) void prop_kernel(
    const float* __restrict__ zcur, const float* __restrict__ zprev,
    float* __restrict__ znext, float* __restrict__ out,
    const int* __restrict__ rowstart, const int* __restrict__ csr_col,
    const float* __restrict__ csr_norm, const float* __restrict__ wkg,
    float alpha, float beta) {
    __shared__ float lds[4][BH];
    __shared__ float wk[BH];
    int t = threadIdx.x;
    for (int i = t; i < BH; i += 256) wk[i] = wkg[i];
    int wv = t >> 6, lane = t & 63;
    int node = blockIdx.x * 4 + wv;

    float acc[6] = {0, 0, 0, 0, 0, 0};
    int e0 = rowstart[node], e1 = rowstart[node + 1];
    for (int e = e0; e < e1; e++) {
        int c = csr_col[e];
        float nrm = csr_norm[e];
        const float* zp = zcur + (size_t)c * BH + lane;
#pragma unroll
        for (int j = 0; j < 6; j++) acc[j] += nrm * zp[64 * j];
    }
    const float* pv = zprev + (size_t)node * BH + lane;
    float* nx = znext + (size_t)node * BH + lane;
#pragma unroll
    for (int j = 0; j < 6; j++) {
        float v = alpha * acc[j] - beta * pv[64 * j];
        nx[64 * j] = v;
        lds[wv][lane + 64 * j] = v;
    }
    __syncthreads();
    float* op = out + (size_t)node * BG;
#pragma unroll
    for (int j2 = 0; j2 < 16; j2++) {
        int idx = lane + 64 * j2;
        int b = idx >> 5, f = idx & 31;
        float s = 0.f;
#pragma unroll
        for (int h = 0; h < HLEN; h++) s += lds[wv][b * HLEN + h] * wk[h * G1 + f];
        op[idx] += s;
    }
}

// ---------------- FC: logits[b,c] = sum_{n,f} relu(out + cb) * fc_w ----------------
__global__ __launch_bounds__(320) void fc_kernel(const float* __restrict__ out,
                                                 const float* __restrict__ conv_b,
                                                 const float* __restrict__ fc_w,
                                                 float* __restrict__ logits) {
    __shared__ float cb[G1];
    int t = threadIdx.x;
    if (t < G1) cb[t] = conv_b[t];
    __syncthreads();
    int b = t / NCLS, c = t % NCLS;
    const int nodes_per = (N_NODES + gridDim.x - 1) / gridDim.x;
    int n0 = blockIdx.x * nodes_per;
    int n1 = n0 + nodes_per;
    if (n1 > N_NODES) n1 = N_NODES;
    float acc = 0.f;
    for (int n = n0; n < n1; n++) {
        const float* op = out + (size_t)n * BG + b * G1;
        const float* wp = fc_w + (size_t)c * (N_NODES * G1) + (size_t)n * G1;
#pragma unroll
        for (int f = 0; f < G1; f++) {
            float v = op[f] + cb[f];
            v = v > 0.f ? v : 0.f;
            acc += v * wp[f];
        }
    }
    atomicAdd(&logits[b * NCLS + c], acc);
}

__global__ void softmax_kernel(const float* __restrict__ logits,
                               const float* __restrict__ fc_b,
                               float* __restrict__ out) {
    int b = threadIdx.x;
    if (b < BATCH) {
        float v[NCLS];
        float m = -1e30f;
#pragma unroll
        for (int c = 0; c < NCLS; c++) {
            v[c] = logits[b * NCLS + c] + fc_b[c];
            m = fmaxf(m, v[c]);
        }
        float s = 0.f;
#pragma unroll
        for (int c = 0; c < NCLS; c++) s += expf(v[c] - m);
        float ls = logf(s);
#pragma unroll
        for (int c = 0; c < NCLS; c++) out[b * NCLS + c] = v[c] - m - ls;
    }
}

extern "C" void kernel_launch(void* const* d_in, const int* in_sizes, int n_in,
                              void* d_out, int out_size, void* d_ws, size_t ws_size,
                              hipStream_t stream) {
    const float* x      = (const float*)d_in[0];
    const int*   ei     = (const int*)d_in[1];
    const float* conv_w = (const float*)d_in[2];
    const float* conv_b = (const float*)d_in[3];
    const float* fc_w   = (const float*)d_in[4];
    const float* fc_b   = (const float*)d_in[5];
    float* outp = (float*)d_out;

    const int* row = ei;
    const int* col = ei + N_EDGES;

    char* ws = (char*)d_ws;
    size_t off = 0;
    auto alloc = [&](size_t bytes) -> void* {
        void* p = ws + off;
        off = (off + bytes + 255) & ~(size_t)255;
        return p;
    };
    float* buf0     = (float*)alloc(sizeof(float) * (size_t)N_NODES * BH);
    float* buf1     = (float*)alloc(sizeof(float) * (size_t)N_NODES * BH);
    float* outacc   = (float*)alloc(sizeof(float) * (size_t)N_NODES * BG);
    int*   cnt      = (int*)alloc(sizeof(int) * N_NODES);
    float* dinv     = (float*)alloc(sizeof(float) * N_NODES);
    int*   rowstart = (int*)alloc(sizeof(int) * (N_NODES + 1));
    int*   cursor   = (int*)alloc(sizeof(int) * N_NODES);
    int*   csr_col  = (int*)alloc(sizeof(int) * N_EDGES);
    float* csr_norm = (float*)alloc(sizeof(float) * N_EDGES);
    float* logits   = (float*)alloc(sizeof(float) * BATCH * NCLS);

    hipMemsetAsync(cnt, 0, sizeof(int) * N_NODES, stream);
    hipMemsetAsync(cursor, 0, sizeof(int) * N_NODES, stream);
    hipMemsetAsync(logits, 0, sizeof(float) * BATCH * NCLS, stream);

    deg_kernel<<<(N_EDGES + 255) / 256, 256, 0, stream>>>(row, cnt);
    dinv_kernel<<<(N_NODES + 255) / 256, 256, 0, stream>>>(cnt, dinv);
    scan_kernel<<<1, 1024, 0, stream>>>(cnt, rowstart);
    scatter_kernel<<<(N_EDGES + 255) / 256, 256, 0, stream>>>(row, col, dinv, rowstart,
                                                              cursor, csr_col, csr_norm);
    fft_kernel<<<(N_NODES * BATCH + 255) / 256, 256, 0, stream>>>(x, buf0);

    // k = 0: out = T0 @ W0
    k0_kernel<<<N_NODES / 4, 256, 0, stream>>>(buf0, outacc, conv_w);
    // k = 1: T1 = Lt @ T0 ; out += T1 @ W1
    prop_kernel<<<N_NODES / 4, 256, 0, stream>>>(buf0, buf0, buf1, outacc, rowstart,
                                                 csr_col, csr_norm, conv_w + 1 * BH,
                                                 1.0f, 0.0f);
    float* zprev = buf0;
    float* zcur  = buf1;
    for (int k = 2; k < KORD; k++) {
        // T_k = 2 Lt T_{k-1} - T_{k-2}  (written over zprev's buffer)
        prop_kernel<<<N_NODES / 4, 256, 0, stream>>>(zcur, zprev, zprev, outacc, rowstart,
                                                     csr_col, csr_norm, conv_w + (size_t)k * BH,
                                                     2.0f, 1.0f);
        float* tmp = zprev; zprev = zcur; zcur = tmp;
    }

    fc_kernel<<<50, 320, 0, stream>>>(outacc, conv_b, fc_w, logits);
    softmax_kernel<<<1, 64, 0, stream>>>(logits, fc_b, outp);
}